// Round 5
// baseline (193.322 us; speedup 1.0000x reference)
//
#include <hip/hip_runtime.h>
#include <hip/hip_bf16.h>

// Node_GAT N=16, M=1024, D=64, H=4.
// R5: S^T-trick flash attention — compute S^T (A=Q, B=K) so P exits MFMA in
// A-operand orientation; lane^32 shfl_xor completes the fragments (no P LDS
// round-trip). 128 i-rows/block halves staging; l = in-register fp32 row-sum.
// prep folded into proj/dec (3 launches). Max-free softmax as before.

#define NB 16
#define MM 1024
#define DD 64
#define HH 4
#define NEG 0.2f
#define AST 72   // LDS row stride in shorts (144 B = 9*16 B: conflict-free)
#define DST 264  // dec LDS stride

typedef __attribute__((ext_vector_type(8))) short bf16x8;
typedef __attribute__((ext_vector_type(8))) _Float16 f16x8;
typedef __attribute__((ext_vector_type(16))) float f32x16;

__device__ inline unsigned short f2bf(float f) {
  unsigned int u = __builtin_bit_cast(unsigned int, f);
  return (unsigned short)((u + 0x7FFFu + ((u >> 16) & 1u)) >> 16);
}
__device__ inline unsigned short f2h(float f) {
  _Float16 h = (_Float16)f;
  return __builtin_bit_cast(unsigned short, h);
}
__device__ inline unsigned int pack_bf16(float a, float b) {
  unsigned int ua = __builtin_bit_cast(unsigned int, a);
  unsigned int ub = __builtin_bit_cast(unsigned int, b);
  ua = (ua + 0x7FFFu + ((ua >> 16) & 1u)) >> 16;
  ub = (ub + 0x7FFFu + ((ub >> 16) & 1u)) & 0xFFFF0000u;
  return ua | ub;
}

// ---------------- Kernel 1: projections, f16 32x32x16 MFMA (inline W cvt) -------
// grid (256, 12): 64 m-rows x combo(mat*4+h). K,Q -> f16 (n,h,m,e); V -> bf16 Vt (n,h,e,m).
__global__ __launch_bounds__(256) void proj_kernel(
    const float* __restrict__ x,
    const float* __restrict__ Wk, const float* __restrict__ Wq, const float* __restrict__ Wv,
    const float* __restrict__ bk, const float* __restrict__ bq, const float* __restrict__ bv,
    unsigned short* __restrict__ Kf, unsigned short* __restrict__ Qf,
    unsigned short* __restrict__ Vtg) {
  __shared__ unsigned short xs[64 * AST];
  __shared__ unsigned short ob[64 * AST];
  const int t = threadIdx.x;
  const int r0 = blockIdx.x * 64;
  const int combo = blockIdx.y, mat = combo >> 2, h = combo & 3;
  const int n = r0 >> 10, ml = r0 & 1023;
  const float* W = mat == 0 ? Wk : (mat == 1 ? Wq : Wv);
  const float* bias = mat == 0 ? bk : (mat == 1 ? bq : bv);

  // stage x tile as f16
#pragma unroll
  for (int rep = 0; rep < 2; ++rep) {
    int idx = rep * 256 + t, row = idx >> 3, c8 = (idx & 7) * 8;
    float4 a = *(const float4*)&x[(size_t)(r0 + row) * DD + c8];
    float4 b = *(const float4*)&x[(size_t)(r0 + row) * DD + c8 + 4];
    unsigned short p[8] = {f2h(a.x), f2h(a.y), f2h(a.z), f2h(a.w),
                           f2h(b.x), f2h(b.y), f2h(b.z), f2h(b.w)};
    *(uint4*)&xs[row * AST + c8] = *(uint4*)p;
  }
  __syncthreads();

  const int w = t >> 6, lane = t & 63, m31 = lane & 31, hf = lane >> 5;
  const int mi = w >> 1, ne = w & 1;
  const int ecol = h * 64 + ne * 32 + m31;
  const float bb = bias[ecol];

  f32x16 C;
#pragma unroll
  for (int r = 0; r < 16; ++r) C[r] = 0.f;
#pragma unroll
  for (int ks = 0; ks < 4; ++ks) {
    f16x8 xa = *(f16x8*)&xs[(mi * 32 + m31) * AST + ks * 16 + hf * 8];
    float4 wa = *(const float4*)&W[(size_t)ecol * DD + ks * 16 + hf * 8];
    float4 wc = *(const float4*)&W[(size_t)ecol * DD + ks * 16 + hf * 8 + 4];
    f16x8 wb;
    wb[0] = (_Float16)wa.x; wb[1] = (_Float16)wa.y; wb[2] = (_Float16)wa.z; wb[3] = (_Float16)wa.w;
    wb[4] = (_Float16)wc.x; wb[5] = (_Float16)wc.y; wb[6] = (_Float16)wc.z; wb[7] = (_Float16)wc.w;
    C = __builtin_amdgcn_mfma_f32_32x32x16_f16(xa, wb, C, 0, 0, 0);
  }

  if (mat < 2) {
#pragma unroll
    for (int r = 0; r < 16; ++r) {
      int rr = (r & 3) + 8 * (r >> 2) + 4 * hf;
      ob[(mi * 32 + rr) * AST + ne * 32 + m31] = f2h(C[r] + bb);
    }
  } else {
#pragma unroll
    for (int r = 0; r < 16; ++r) {
      int rr = (r & 3) + 8 * (r >> 2) + 4 * hf;
      ob[(ne * 32 + m31) * AST + mi * 32 + rr] = f2bf(C[r] + bb);
    }
  }
  __syncthreads();

  if (mat < 2) {
    unsigned short* dst = mat == 0 ? Kf : Qf;
    const size_t obase = (((size_t)n * HH + h) * MM + ml) * DD;
#pragma unroll
    for (int rep = 0; rep < 2; ++rep) {
      int idx = rep * 256 + t, row = idx >> 3, c8 = (idx & 7) * 8;
      *(uint4*)&dst[obase + (size_t)row * DD + c8] = *(uint4*)&ob[row * AST + c8];
    }
  } else {
    const size_t obase = (((size_t)n * HH + h) * DD) * MM + ml;
#pragma unroll
    for (int rep = 0; rep < 2; ++rep) {
      int idx = rep * 256 + t, row = idx >> 3, c8 = (idx & 7) * 8;  // row = e
      *(uint4*)&Vtg[obase + (size_t)row * MM + c8] = *(uint4*)&ob[row * AST + c8];
    }
  }
}

// ---------------- Kernel 2: flash attention, S^T + shfl P-transform ----------------
// grid (8, H, N), 256 thr = 4 waves. Block: 128 i-rows; wave w owns i = w*32..+32,
// all j (1024) and all e (64). S^T: A=Q (LDS), B=K (regs) -> C'[j in regs][i in lanes].
__global__ __launch_bounds__(256) void attn_kernel(
    const unsigned short* __restrict__ Kf, const unsigned short* __restrict__ Qf,
    const unsigned short* __restrict__ Vtg, const float* __restrict__ x,
    unsigned short* __restrict__ DX) {
  __shared__ unsigned short smem[2 * 64 * AST];  // qh | vt ; reused as dxb[128][AST]
  __shared__ float ls[128];
  unsigned short* qh = smem;            // Q f16 [j_local][e]
  unsigned short* vt = smem + 64 * AST; // V^T bf16 [e][j_local]

  const int t = threadIdx.x;
  const int w = t >> 6, lane = t & 63, m31 = lane & 31, hf = lane >> 5;
  const int i0 = blockIdx.x * 128, h = blockIdx.y, n = blockIdx.z;
  const size_t base = (((size_t)n * HH + h) * MM) * DD;
  const size_t baseT = (((size_t)n * HH + h) * DD) * MM;
  const int iw = i0 + w * 32 + m31;  // this lane's i row

  // K B-frags (f16), row i = iw, k = e
  f16x8 kf[4];
#pragma unroll
  for (int ks = 0; ks < 4; ++ks)
    kf[ks] = *(const f16x8*)&Kf[base + (size_t)iw * DD + ks * 16 + hf * 8];

  f32x16 agg0, agg1;
#pragma unroll
  for (int r = 0; r < 16; ++r) { agg0[r] = 0.f; agg1[r] = 0.f; }
  float lsum = 0.f;

  for (int jt = 0; jt < 16; ++jt) {
    const int j0 = jt * 64;
    __syncthreads();
#pragma unroll
    for (int rep = 0; rep < 2; ++rep) {
      int idx = rep * 256 + t, row = idx >> 3, c8 = (idx & 7) * 8;
      *(uint4*)&qh[row * AST + c8] = *(const uint4*)&Qf[base + (size_t)(j0 + row) * DD + c8];
      *(uint4*)&vt[row * AST + c8] = *(const uint4*)&Vtg[baseT + (size_t)row * MM + j0 + c8];
    }
    __syncthreads();

    // S^T tiles (t2 = j-half): C'[r] = S[i=iw][j = j0 + t2*32 + rr]
    unsigned int pk[16];
#pragma unroll
    for (int t2 = 0; t2 < 2; ++t2) {
      f32x16 C;
#pragma unroll
      for (int r = 0; r < 16; ++r) C[r] = 0.f;
#pragma unroll
      for (int ks = 0; ks < 4; ++ks) {
        f16x8 qa = *(f16x8*)&qh[(t2 * 32 + m31) * AST + ks * 16 + hf * 8];
        C = __builtin_amdgcn_mfma_f32_32x32x16_f16(qa, kf[ks], C, 0, 0, 0);
      }
#pragma unroll
      for (int g = 0; g < 4; ++g) {
        float p0 = C[4 * g + 0], p1 = C[4 * g + 1], p2 = C[4 * g + 2], p3 = C[4 * g + 3];
        p0 = __expf(fmaxf(p0, NEG * p0));
        p1 = __expf(fmaxf(p1, NEG * p1));
        p2 = __expf(fmaxf(p2, NEG * p2));
        p3 = __expf(fmaxf(p3, NEG * p3));
        lsum += (p0 + p1) + (p2 + p3);
        pk[t2 * 8 + g * 2]     = pack_bf16(p0, p1);
        pk[t2 * 8 + g * 2 + 1] = pack_bf16(p2, p3);
      }
    }

    // PV: assemble P A-frags (k = j_local) via lane^32 exchange, multiply V^T
#pragma unroll
    for (int ks = 0; ks < 4; ++ks) {
      const int b = (ks >> 1) * 8, gl2 = (ks & 1) * 4, gh2 = gl2 + 2;
      unsigned int sA = hf ? pk[b + gl2]     : pk[b + gh2];
      unsigned int sB = hf ? pk[b + gl2 + 1] : pk[b + gh2 + 1];
      unsigned int rA = (unsigned int)__shfl_xor((int)sA, 32);
      unsigned int rB = (unsigned int)__shfl_xor((int)sB, 32);
      union { unsigned int u[4]; bf16x8 v; } cv;
      cv.u[0] = hf ? rA : pk[b + gl2];
      cv.u[1] = hf ? rB : pk[b + gl2 + 1];
      cv.u[2] = hf ? pk[b + gh2]     : rA;
      cv.u[3] = hf ? pk[b + gh2 + 1] : rB;
      bf16x8 bV0 = *(bf16x8*)&vt[m31 * AST + ks * 16 + hf * 8];
      bf16x8 bV1 = *(bf16x8*)&vt[(32 + m31) * AST + ks * 16 + hf * 8];
      agg0 = __builtin_amdgcn_mfma_f32_32x32x16_bf16(cv.v, bV0, agg0, 0, 0, 0);
      agg1 = __builtin_amdgcn_mfma_f32_32x32x16_bf16(cv.v, bV1, agg1, 0, 0, 0);
    }
  }

  // row-sum l: this lane + partner cover all j for row iw
  lsum += __shfl_xor(lsum, 32);
  if (hf == 0) ls[w * 32 + m31] = lsum;
  __syncthreads();  // all PV reads done; ls visible; smem reusable as dxb

  // epilogue: dx = leaky(agg/l) - x -> f16 staged in smem, coalesced store
  unsigned short* dxb = smem;  // [128][AST]
  float invl[16];
#pragma unroll
  for (int r = 0; r < 16; ++r) {
    int rr = (r & 3) + 8 * (r >> 2) + 4 * hf;
    invl[r] = 1.0f / ls[w * 32 + rr];
  }
#pragma unroll
  for (int half = 0; half < 2; ++half) {
    const int e = half * 32 + m31;
#pragma unroll
    for (int r = 0; r < 16; ++r) {
      int rr = (r & 3) + 8 * (r >> 2) + 4 * hf;
      float v = (half ? agg1[r] : agg0[r]) * invl[r];
      v = fmaxf(v, NEG * v);
      v -= x[((size_t)n * MM + i0 + w * 32 + rr) * DD + e];
      dxb[(w * 32 + rr) * AST + e] = f2h(v);
    }
  }
  __syncthreads();
#pragma unroll
  for (int rep = 0; rep < 4; ++rep) {
    int idx = rep * 256 + t, row = idx >> 3, c8 = (idx & 7) * 8;
    *(uint4*)&DX[((size_t)n * MM + i0 + row) * (HH * DD) + h * DD + c8] =
        *(uint4*)&dxb[row * AST + c8];
  }
}

// ---------------- Kernel 3: decoder, f16 32x32x16 MFMA (inline W cvt) ----------------
__global__ __launch_bounds__(256) void dec_kernel(
    const unsigned short* __restrict__ DX, const float* __restrict__ Wdec,
    const float* __restrict__ bdec, float* __restrict__ out) {
  __shared__ unsigned short dxs[64 * DST];
  const int t = threadIdx.x;
  const int w = t >> 6, lane = t & 63, m31 = lane & 31, hf = lane >> 5;
  const int mi = w >> 1, nd = w & 1;
  const int r0 = blockIdx.x * 64;
#pragma unroll
  for (int rep = 0; rep < 8; ++rep) {
    int idx = rep * 256 + t, row = idx >> 5, c8 = (idx & 31) * 8;
    *(uint4*)&dxs[row * DST + c8] = *(const uint4*)&DX[(size_t)(r0 + row) * 256 + c8];
  }
  __syncthreads();
  const float bb = bdec[nd * 32 + m31];
  f32x16 C;
#pragma unroll
  for (int r = 0; r < 16; ++r) C[r] = 0.f;
#pragma unroll
  for (int ks = 0; ks < 16; ++ks) {
    f16x8 aD = *(f16x8*)&dxs[(mi * 32 + m31) * DST + ks * 16 + hf * 8];
    float4 wa = *(const float4*)&Wdec[(size_t)(nd * 32 + m31) * 256 + ks * 16 + hf * 8];
    float4 wc = *(const float4*)&Wdec[(size_t)(nd * 32 + m31) * 256 + ks * 16 + hf * 8 + 4];
    f16x8 bW;
    bW[0] = (_Float16)wa.x; bW[1] = (_Float16)wa.y; bW[2] = (_Float16)wa.z; bW[3] = (_Float16)wa.w;
    bW[4] = (_Float16)wc.x; bW[5] = (_Float16)wc.y; bW[6] = (_Float16)wc.z; bW[7] = (_Float16)wc.w;
    C = __builtin_amdgcn_mfma_f32_32x32x16_f16(aD, bW, C, 0, 0, 0);
  }
#pragma unroll
  for (int r = 0; r < 16; ++r) {
    int rr = (r & 3) + 8 * (r >> 2) + 4 * hf;
    out[(size_t)(r0 + mi * 32 + rr) * DD + nd * 32 + m31] = C[r] + bb;
  }
}

extern "C" void kernel_launch(void* const* d_in, const int* in_sizes, int n_in,
                              void* d_out, int out_size, void* d_ws, size_t ws_size,
                              hipStream_t stream) {
  const float* x    = (const float*)d_in[0];
  const float* Wk   = (const float*)d_in[2];
  const float* bk   = (const float*)d_in[3];
  const float* Wq   = (const float*)d_in[4];
  const float* bq   = (const float*)d_in[5];
  const float* Wv   = (const float*)d_in[6];
  const float* bv   = (const float*)d_in[7];
  const float* Wdec = (const float*)d_in[8];
  const float* bdec = (const float*)d_in[9];
  float* out = (float*)d_out;

  // ws (shorts): Kf | Qf | Vt | DX, each N*H*M*D = 4,194,304
  const size_t seg = (size_t)NB * HH * MM * DD;
  unsigned short* Kf  = (unsigned short*)d_ws;
  unsigned short* Qf  = Kf + seg;
  unsigned short* Vt  = Qf + seg;
  unsigned short* DXp = Vt + seg;

  proj_kernel<<<dim3(256, 12), 256, 0, stream>>>(x, Wk, Wq, Wv, bk, bq, bv, Kf, Qf, Vt);
  attn_kernel<<<dim3(8, HH, NB), 256, 0, stream>>>(Kf, Qf, Vt, x, DXp);
  dec_kernel<<<NB * MM / 64, 256, 0, stream>>>(DXp, Wdec, bdec, out);
}

// Round 6
// 166.595 us; speedup vs baseline: 1.1604x; 1.1604x over previous
//
#include <hip/hip_runtime.h>
#include <hip/hip_bf16.h>

// Node_GAT N=16, M=1024, D=64, H=4.
// R6: S^T-trick attention (R5) restored to 1024-block grid: 64 i/block, 4 waves
// = (i-tile ih) x (j-half jh); per-wave partial agg over its j-half, block-end
// LDS reduce. dec reparallelized (32 rows/block, K-split waves). Max-free
// softmax (leaky scores bounded, exp fits fp32) as before.

#define NB 16
#define MM 1024
#define DD 64
#define HH 4
#define NEG 0.2f
#define AST 72   // LDS row stride in shorts (144 B = 9*16 B)
#define DST 264  // dec LDS stride (shorts)

typedef __attribute__((ext_vector_type(8))) short bf16x8;
typedef __attribute__((ext_vector_type(8))) _Float16 f16x8;
typedef __attribute__((ext_vector_type(16))) float f32x16;

__device__ inline unsigned short f2bf(float f) {
  unsigned int u = __builtin_bit_cast(unsigned int, f);
  return (unsigned short)((u + 0x7FFFu + ((u >> 16) & 1u)) >> 16);
}
__device__ inline unsigned short f2h(float f) {
  _Float16 h = (_Float16)f;
  return __builtin_bit_cast(unsigned short, h);
}
__device__ inline unsigned int pack_bf16(float a, float b) {
  unsigned int ua = __builtin_bit_cast(unsigned int, a);
  unsigned int ub = __builtin_bit_cast(unsigned int, b);
  ua = (ua + 0x7FFFu + ((ua >> 16) & 1u)) >> 16;
  ub = (ub + 0x7FFFu + ((ub >> 16) & 1u)) & 0xFFFF0000u;
  return ua | ub;
}

// ---------------- Kernel 1: projections, f16 32x32x16 MFMA (inline W cvt) -------
// grid (256, 12): 64 m-rows x combo(mat*4+h). K,Q -> f16 (n,h,m,e); V -> bf16 Vt (n,h,e,m).
__global__ __launch_bounds__(256) void proj_kernel(
    const float* __restrict__ x,
    const float* __restrict__ Wk, const float* __restrict__ Wq, const float* __restrict__ Wv,
    const float* __restrict__ bk, const float* __restrict__ bq, const float* __restrict__ bv,
    unsigned short* __restrict__ Kf, unsigned short* __restrict__ Qf,
    unsigned short* __restrict__ Vtg) {
  __shared__ unsigned short xs[64 * AST];
  __shared__ unsigned short ob[64 * AST];
  const int t = threadIdx.x;
  const int r0 = blockIdx.x * 64;
  const int combo = blockIdx.y, mat = combo >> 2, h = combo & 3;
  const int n = r0 >> 10, ml = r0 & 1023;
  const float* W = mat == 0 ? Wk : (mat == 1 ? Wq : Wv);
  const float* bias = mat == 0 ? bk : (mat == 1 ? bq : bv);

#pragma unroll
  for (int rep = 0; rep < 2; ++rep) {
    int idx = rep * 256 + t, row = idx >> 3, c8 = (idx & 7) * 8;
    float4 a = *(const float4*)&x[(size_t)(r0 + row) * DD + c8];
    float4 b = *(const float4*)&x[(size_t)(r0 + row) * DD + c8 + 4];
    unsigned short p[8] = {f2h(a.x), f2h(a.y), f2h(a.z), f2h(a.w),
                           f2h(b.x), f2h(b.y), f2h(b.z), f2h(b.w)};
    *(uint4*)&xs[row * AST + c8] = *(uint4*)p;
  }
  __syncthreads();

  const int w = t >> 6, lane = t & 63, m31 = lane & 31, hf = lane >> 5;
  const int mi = w >> 1, ne = w & 1;
  const int ecol = h * 64 + ne * 32 + m31;
  const float bb = bias[ecol];

  f32x16 C;
#pragma unroll
  for (int r = 0; r < 16; ++r) C[r] = 0.f;
#pragma unroll
  for (int ks = 0; ks < 4; ++ks) {
    f16x8 xa = *(f16x8*)&xs[(mi * 32 + m31) * AST + ks * 16 + hf * 8];
    float4 wa = *(const float4*)&W[(size_t)ecol * DD + ks * 16 + hf * 8];
    float4 wc = *(const float4*)&W[(size_t)ecol * DD + ks * 16 + hf * 8 + 4];
    f16x8 wb;
    wb[0] = (_Float16)wa.x; wb[1] = (_Float16)wa.y; wb[2] = (_Float16)wa.z; wb[3] = (_Float16)wa.w;
    wb[4] = (_Float16)wc.x; wb[5] = (_Float16)wc.y; wb[6] = (_Float16)wc.z; wb[7] = (_Float16)wc.w;
    C = __builtin_amdgcn_mfma_f32_32x32x16_f16(xa, wb, C, 0, 0, 0);
  }

  if (mat < 2) {
#pragma unroll
    for (int r = 0; r < 16; ++r) {
      int rr = (r & 3) + 8 * (r >> 2) + 4 * hf;
      ob[(mi * 32 + rr) * AST + ne * 32 + m31] = f2h(C[r] + bb);
    }
  } else {
#pragma unroll
    for (int r = 0; r < 16; ++r) {
      int rr = (r & 3) + 8 * (r >> 2) + 4 * hf;
      ob[(ne * 32 + m31) * AST + mi * 32 + rr] = f2bf(C[r] + bb);
    }
  }
  __syncthreads();

  if (mat < 2) {
    unsigned short* dst = mat == 0 ? Kf : Qf;
    const size_t obase = (((size_t)n * HH + h) * MM + ml) * DD;
#pragma unroll
    for (int rep = 0; rep < 2; ++rep) {
      int idx = rep * 256 + t, row = idx >> 3, c8 = (idx & 7) * 8;
      *(uint4*)&dst[obase + (size_t)row * DD + c8] = *(uint4*)&ob[row * AST + c8];
    }
  } else {
    const size_t obase = (((size_t)n * HH + h) * DD) * MM + ml;
#pragma unroll
    for (int rep = 0; rep < 2; ++rep) {
      int idx = rep * 256 + t, row = idx >> 3, c8 = (idx & 7) * 8;  // row = e
      *(uint4*)&Vtg[obase + (size_t)row * MM + c8] = *(uint4*)&ob[row * AST + c8];
    }
  }
}

// ---------------- Kernel 2: flash attention, S^T + shfl, 64 i/block ----------------
// grid (16, H, N), 256 thr = 4 waves: wave w -> ih = w>>1 (i-tile), jh = w&1 (j-half).
// Each wave: S^T for (32i, 32j-half) -> exp -> P A-frags via lane^32 shfl -> partial
// PV over its j-half. Block end: agg reduce (LDS) across jh pairs, l via lsp.
__global__ __launch_bounds__(256, 4) void attn_kernel(
    const unsigned short* __restrict__ Kf, const unsigned short* __restrict__ Qf,
    const unsigned short* __restrict__ Vtg, const float* __restrict__ x,
    unsigned short* __restrict__ DX) {
  __shared__ unsigned short smem[2 * 64 * AST];  // qh | vt ; end: red = float[4608]
  __shared__ float lsp[2][64];
  unsigned short* qh = smem;             // Q f16 [j_local][e]
  unsigned short* vt = smem + 64 * AST;  // V^T bf16 [e][j_local]

  const int t = threadIdx.x;
  const int w = t >> 6, lane = t & 63, m31 = lane & 31, hf = lane >> 5;
  const int ih = w >> 1, jh = w & 1;
  const int i0 = blockIdx.x * 64, h = blockIdx.y, n = blockIdx.z;
  const size_t base = (((size_t)n * HH + h) * MM) * DD;
  const size_t baseT = (((size_t)n * HH + h) * DD) * MM;
  const int irow = i0 + ih * 32 + m31;

  // K B-frags (f16): B[k=e][col=i=m31]
  f16x8 kf[4];
#pragma unroll
  for (int ks = 0; ks < 4; ++ks)
    kf[ks] = *(const f16x8*)&Kf[base + (size_t)irow * DD + ks * 16 + hf * 8];

  f32x16 agg0, agg1;
#pragma unroll
  for (int r = 0; r < 16; ++r) { agg0[r] = 0.f; agg1[r] = 0.f; }
  float lsum = 0.f;

  for (int jt = 0; jt < 16; ++jt) {
    const int j0 = jt * 64;
    __syncthreads();
#pragma unroll
    for (int rep = 0; rep < 2; ++rep) {
      int idx = rep * 256 + t, row = idx >> 3, c8 = (idx & 7) * 8;
      *(uint4*)&qh[row * AST + c8] = *(const uint4*)&Qf[base + (size_t)(j0 + row) * DD + c8];
      *(uint4*)&vt[row * AST + c8] = *(const uint4*)&Vtg[baseT + (size_t)row * MM + j0 + c8];
    }
    __syncthreads();

    // S^T for this j-half: C[r] = S[i=irow][j = j0 + jh*32 + rr]
    f32x16 C;
#pragma unroll
    for (int r = 0; r < 16; ++r) C[r] = 0.f;
#pragma unroll
    for (int ks = 0; ks < 4; ++ks) {
      f16x8 qa = *(f16x8*)&qh[(jh * 32 + m31) * AST + ks * 16 + hf * 8];
      C = __builtin_amdgcn_mfma_f32_32x32x16_f16(qa, kf[ks], C, 0, 0, 0);
    }
    unsigned int pk[8];
#pragma unroll
    for (int g = 0; g < 4; ++g) {
      float p0 = C[4 * g + 0], p1 = C[4 * g + 1], p2 = C[4 * g + 2], p3 = C[4 * g + 3];
      p0 = __expf(fmaxf(p0, NEG * p0));
      p1 = __expf(fmaxf(p1, NEG * p1));
      p2 = __expf(fmaxf(p2, NEG * p2));
      p3 = __expf(fmaxf(p3, NEG * p3));
      lsum += (p0 + p1) + (p2 + p3);
      pk[g * 2]     = pack_bf16(p0, p1);
      pk[g * 2 + 1] = pack_bf16(p2, p3);
    }

    // PV over this j-half: A-frags via lane^32 exchange; k = j-local (2 steps of 16)
#pragma unroll
    for (int kk = 0; kk < 2; ++kk) {
      const int gl2 = kk * 4, gh2 = kk * 4 + 2;
      unsigned int sA = hf ? pk[gl2]     : pk[gh2];
      unsigned int sB = hf ? pk[gl2 + 1] : pk[gh2 + 1];
      unsigned int rA = (unsigned int)__shfl_xor((int)sA, 32);
      unsigned int rB = (unsigned int)__shfl_xor((int)sB, 32);
      union { unsigned int u[4]; bf16x8 v; } cv;
      cv.u[0] = hf ? rA : pk[gl2];
      cv.u[1] = hf ? rB : pk[gl2 + 1];
      cv.u[2] = hf ? pk[gh2]     : rA;
      cv.u[3] = hf ? pk[gh2 + 1] : rB;
      bf16x8 bV0 = *(bf16x8*)&vt[m31 * AST + jh * 32 + kk * 16 + hf * 8];
      bf16x8 bV1 = *(bf16x8*)&vt[(32 + m31) * AST + jh * 32 + kk * 16 + hf * 8];
      agg0 = __builtin_amdgcn_mfma_f32_32x32x16_bf16(cv.v, bV0, agg0, 0, 0, 0);
      agg1 = __builtin_amdgcn_mfma_f32_32x32x16_bf16(cv.v, bV1, agg1, 0, 0, 0);
    }
  }

  // lane + lane^32 cover this wave's j-half fully for row irow
  lsum += __shfl_xor(lsum, 32);
  __syncthreads();  // all PV reads of vt done; smem reusable as red
  if (hf == 0) lsp[jh][ih * 32 + m31] = lsum;
  float* red = (float*)smem;            // [2][32 lanes][2 hf][36-stride] = 4608 floats
  const int slot = ih * 2304 + m31 * 72 + hf * 36;
  if (jh == 1) {
#pragma unroll
    for (int c = 0; c < 4; ++c) {
      *(float4*)&red[slot + 4 * c]      = make_float4(agg0[4*c], agg0[4*c+1], agg0[4*c+2], agg0[4*c+3]);
      *(float4*)&red[slot + 16 + 4 * c] = make_float4(agg1[4*c], agg1[4*c+1], agg1[4*c+2], agg1[4*c+3]);
    }
  }
  __syncthreads();
  if (jh == 0) {
#pragma unroll
    for (int c = 0; c < 4; ++c) {
      float4 v0 = *(float4*)&red[slot + 4 * c];
      float4 v1 = *(float4*)&red[slot + 16 + 4 * c];
      agg0[4*c] += v0.x; agg0[4*c+1] += v0.y; agg0[4*c+2] += v0.z; agg0[4*c+3] += v0.w;
      agg1[4*c] += v1.x; agg1[4*c+1] += v1.y; agg1[4*c+2] += v1.z; agg1[4*c+3] += v1.w;
    }
    float invl[16];
#pragma unroll
    for (int r = 0; r < 16; ++r) {
      int rr = (r & 3) + 8 * (r >> 2) + 4 * hf;
      invl[r] = 1.0f / (lsp[0][ih * 32 + rr] + lsp[1][ih * 32 + rr]);
    }
#pragma unroll
    for (int r = 0; r < 16; ++r) {
      int rr = (r & 3) + 8 * (r >> 2) + 4 * hf;
      const size_t row = (size_t)n * MM + i0 + ih * 32 + rr;
      float v0 = agg0[r] * invl[r];
      v0 = fmaxf(v0, NEG * v0);
      v0 -= x[row * DD + m31];
      DX[row * (HH * DD) + h * DD + m31] = f2h(v0);
      float v1 = agg1[r] * invl[r];
      v1 = fmaxf(v1, NEG * v1);
      v1 -= x[row * DD + 32 + m31];
      DX[row * (HH * DD) + h * DD + 32 + m31] = f2h(v1);
    }
  }
}

// ---------------- Kernel 3: decoder, 32 rows/block, K-split waves ----------------
// grid 512: wave w -> nd = w&1 (col-half), kq = w>>1 (K-half of 256). End: LDS reduce.
__global__ __launch_bounds__(256) void dec_kernel(
    const unsigned short* __restrict__ DX, const float* __restrict__ Wdec,
    const float* __restrict__ bdec, float* __restrict__ out) {
  __shared__ unsigned short dxs[32 * DST];
  __shared__ float red2[2 * 64 * 20];
  const int t = threadIdx.x;
  const int w = t >> 6, lane = t & 63, m31 = lane & 31, hf = lane >> 5;
  const int nd = w & 1, kq = w >> 1;
  const int r0 = blockIdx.x * 32;
#pragma unroll
  for (int rep = 0; rep < 4; ++rep) {
    int idx = rep * 256 + t, row = idx >> 5, c8 = (idx & 31) * 8;
    *(uint4*)&dxs[row * DST + c8] = *(const uint4*)&DX[(size_t)(r0 + row) * 256 + c8];
  }
  __syncthreads();
  f32x16 C;
#pragma unroll
  for (int r = 0; r < 16; ++r) C[r] = 0.f;
#pragma unroll
  for (int ks = 0; ks < 8; ++ks) {
    const int koff = kq * 128 + ks * 16 + hf * 8;
    f16x8 aD = *(f16x8*)&dxs[m31 * DST + koff];
    float4 wa = *(const float4*)&Wdec[(size_t)(nd * 32 + m31) * 256 + koff];
    float4 wc = *(const float4*)&Wdec[(size_t)(nd * 32 + m31) * 256 + koff + 4];
    f16x8 bW;
    bW[0] = (_Float16)wa.x; bW[1] = (_Float16)wa.y; bW[2] = (_Float16)wa.z; bW[3] = (_Float16)wa.w;
    bW[4] = (_Float16)wc.x; bW[5] = (_Float16)wc.y; bW[6] = (_Float16)wc.z; bW[7] = (_Float16)wc.w;
    C = __builtin_amdgcn_mfma_f32_32x32x16_f16(aD, bW, C, 0, 0, 0);
  }
  const int slot = nd * 64 * 20 + (hf * 32 + m31) * 20;
  if (kq == 1) {
#pragma unroll
    for (int c = 0; c < 4; ++c)
      *(float4*)&red2[slot + 4 * c] = make_float4(C[4*c], C[4*c+1], C[4*c+2], C[4*c+3]);
  }
  __syncthreads();
  if (kq == 0) {
#pragma unroll
    for (int c = 0; c < 4; ++c) {
      float4 v = *(float4*)&red2[slot + 4 * c];
      C[4*c] += v.x; C[4*c+1] += v.y; C[4*c+2] += v.z; C[4*c+3] += v.w;
    }
    const float bb = bdec[nd * 32 + m31];
#pragma unroll
    for (int r = 0; r < 16; ++r) {
      int rr = (r & 3) + 8 * (r >> 2) + 4 * hf;
      out[(size_t)(r0 + rr) * DD + nd * 32 + m31] = C[r] + bb;
    }
  }
}

extern "C" void kernel_launch(void* const* d_in, const int* in_sizes, int n_in,
                              void* d_out, int out_size, void* d_ws, size_t ws_size,
                              hipStream_t stream) {
  const float* x    = (const float*)d_in[0];
  const float* Wk   = (const float*)d_in[2];
  const float* bk   = (const float*)d_in[3];
  const float* Wq   = (const float*)d_in[4];
  const float* bq   = (const float*)d_in[5];
  const float* Wv   = (const float*)d_in[6];
  const float* bv   = (const float*)d_in[7];
  const float* Wdec = (const float*)d_in[8];
  const float* bdec = (const float*)d_in[9];
  float* out = (float*)d_out;

  // ws (shorts): Kf | Qf | Vt | DX, each N*H*M*D = 4,194,304
  const size_t seg = (size_t)NB * HH * MM * DD;
  unsigned short* Kf  = (unsigned short*)d_ws;
  unsigned short* Qf  = Kf + seg;
  unsigned short* Vt  = Qf + seg;
  unsigned short* DXp = Vt + seg;

  proj_kernel<<<dim3(256, 12), 256, 0, stream>>>(x, Wk, Wq, Wv, bk, bq, bv, Kf, Qf, Vt);
  attn_kernel<<<dim3(16, HH, NB), 256, 0, stream>>>(Kf, Qf, Vt, x, DXp);
  dec_kernel<<<NB * MM / 32, 256, 0, stream>>>(DXp, Wdec, bdec, out);
}

// Round 9
// 162.199 us; speedup vs baseline: 1.1919x; 1.0271x over previous
//
#include <hip/hip_runtime.h>
#include <hip/hip_bf16.h>

// Node_GAT N=16, M=1024, D=64, H=4.
// R9: fixes R7/R8's real bug — dec_kernel only summed K=[0,128) of 256 (the
// kq-split was dropped in the LDS-free rewrite but the loop count stayed 8).
// Now 16 MFMA covering the full K=256. (R8's pack "fix" was a red herring:
// absmax was bit-identical across R7/R8, proving the perm pack was correct.)
// Kept: K pre-scaled by log2(e) -> p = v_exp_f32(leaky(s)); truncating bf16
// pack; Q/V register prefetch; merged proj (K,Q,V per block + f16 Wdec);
// LDS-free dec.

#define NB 16
#define MM 1024
#define DD 64
#define HH 4
#define NEG 0.2f
#define L2E 1.44269504f
#define AST 72   // LDS row stride in shorts (144 B)

typedef __attribute__((ext_vector_type(8))) short bf16x8;
typedef __attribute__((ext_vector_type(8))) _Float16 f16x8;
typedef __attribute__((ext_vector_type(16))) float f32x16;

__device__ inline unsigned short f2bf(float f) {
  unsigned int u = __builtin_bit_cast(unsigned int, f);
  return (unsigned short)((u + 0x7FFFu + ((u >> 16) & 1u)) >> 16);
}
__device__ inline unsigned short f2h(float f) {
  _Float16 h = (_Float16)f;
  return __builtin_bit_cast(unsigned short, h);
}
// truncating pack: lo16 = bf16(a), hi16 = bf16(b).
__device__ inline unsigned int pack_bf16_tr(float a, float b) {
  unsigned int ua = __builtin_bit_cast(unsigned int, a);
  unsigned int ub = __builtin_bit_cast(unsigned int, b);
  return (ua >> 16) | (ub & 0xFFFF0000u);
}
__device__ inline f16x8 cvtW8(const float* p) {
  float4 a = *(const float4*)p;
  float4 b = *(const float4*)(p + 4);
  f16x8 r;
  r[0] = (_Float16)a.x; r[1] = (_Float16)a.y; r[2] = (_Float16)a.z; r[3] = (_Float16)a.w;
  r[4] = (_Float16)b.x; r[5] = (_Float16)b.y; r[6] = (_Float16)b.z; r[7] = (_Float16)b.w;
  return r;
}

// ---------------- Kernel 1: projections, all 3 mats per block ----------------
// grid (256, 4): 64 m-rows x head h. K (pre-scaled by log2e), Q -> f16 (n,h,m,e);
// V -> bf16 Vt (n,h,e,m). Also converts Wdec -> f16 (h==0, bx<16).
__global__ __launch_bounds__(256) void proj_kernel(
    const float* __restrict__ x,
    const float* __restrict__ Wk, const float* __restrict__ Wq, const float* __restrict__ Wv,
    const float* __restrict__ bk, const float* __restrict__ bq, const float* __restrict__ bv,
    const float* __restrict__ Wdec,
    unsigned short* __restrict__ Kf, unsigned short* __restrict__ Qf,
    unsigned short* __restrict__ Vtg, unsigned short* __restrict__ Wdf) {
  __shared__ unsigned short xs[64 * AST];
  __shared__ unsigned short ob[64 * AST];
  const int t = threadIdx.x;
  const int r0 = blockIdx.x * 64;
  const int h = blockIdx.y;
  const int n = r0 >> 10, ml = r0 & 1023;

  if (h == 0 && blockIdx.x < 16) {  // piggyback Wdec fp32->f16
    int idx = (blockIdx.x * 256 + t) * 4;
    float4 v = *(const float4*)&Wdec[idx];
    unsigned short p[4] = {f2h(v.x), f2h(v.y), f2h(v.z), f2h(v.w)};
    *(uint2*)&Wdf[idx] = *(uint2*)p;
  }

  // stage x tile as f16
#pragma unroll
  for (int rep = 0; rep < 2; ++rep) {
    int idx = rep * 256 + t, row = idx >> 3, c8 = (idx & 7) * 8;
    float4 a = *(const float4*)&x[(size_t)(r0 + row) * DD + c8];
    float4 b = *(const float4*)&x[(size_t)(r0 + row) * DD + c8 + 4];
    unsigned short p[8] = {f2h(a.x), f2h(a.y), f2h(a.z), f2h(a.w),
                           f2h(b.x), f2h(b.y), f2h(b.z), f2h(b.w)};
    *(uint4*)&xs[row * AST + c8] = *(uint4*)p;
  }
  __syncthreads();

  const int w = t >> 6, lane = t & 63, m31 = lane & 31, hf = lane >> 5;
  const int mi = w >> 1, ne = w & 1;
  const int ecol = h * 64 + ne * 32 + m31;

  f32x16 Ck, Cq, Cv;
#pragma unroll
  for (int r = 0; r < 16; ++r) { Ck[r] = 0.f; Cq[r] = 0.f; Cv[r] = 0.f; }
#pragma unroll
  for (int ks = 0; ks < 4; ++ks) {
    f16x8 xa = *(f16x8*)&xs[(mi * 32 + m31) * AST + ks * 16 + hf * 8];
    f16x8 wk8 = cvtW8(&Wk[(size_t)ecol * DD + ks * 16 + hf * 8]);
    Ck = __builtin_amdgcn_mfma_f32_32x32x16_f16(xa, wk8, Ck, 0, 0, 0);
    f16x8 wq8 = cvtW8(&Wq[(size_t)ecol * DD + ks * 16 + hf * 8]);
    Cq = __builtin_amdgcn_mfma_f32_32x32x16_f16(xa, wq8, Cq, 0, 0, 0);
    f16x8 wv8 = cvtW8(&Wv[(size_t)ecol * DD + ks * 16 + hf * 8]);
    Cv = __builtin_amdgcn_mfma_f32_32x32x16_f16(xa, wv8, Cv, 0, 0, 0);
  }
  const float bbk = bk[ecol], bbq = bq[ecol], bbv = bv[ecol];

  const size_t obase = (((size_t)n * HH + h) * MM + ml) * DD;
  const size_t obaseT = (((size_t)n * HH + h) * DD) * MM + ml;

  // K (scaled by log2e)
#pragma unroll
  for (int r = 0; r < 16; ++r) {
    int rr = (r & 3) + 8 * (r >> 2) + 4 * hf;
    ob[(mi * 32 + rr) * AST + ne * 32 + m31] = f2h((Ck[r] + bbk) * L2E);
  }
  __syncthreads();
#pragma unroll
  for (int rep = 0; rep < 2; ++rep) {
    int idx = rep * 256 + t, row = idx >> 3, c8 = (idx & 7) * 8;
    *(uint4*)&Kf[obase + (size_t)row * DD + c8] = *(uint4*)&ob[row * AST + c8];
  }
  __syncthreads();
  // Q
#pragma unroll
  for (int r = 0; r < 16; ++r) {
    int rr = (r & 3) + 8 * (r >> 2) + 4 * hf;
    ob[(mi * 32 + rr) * AST + ne * 32 + m31] = f2h(Cq[r] + bbq);
  }
  __syncthreads();
#pragma unroll
  for (int rep = 0; rep < 2; ++rep) {
    int idx = rep * 256 + t, row = idx >> 3, c8 = (idx & 7) * 8;
    *(uint4*)&Qf[obase + (size_t)row * DD + c8] = *(uint4*)&ob[row * AST + c8];
  }
  __syncthreads();
  // V transposed, bf16
#pragma unroll
  for (int r = 0; r < 16; ++r) {
    int rr = (r & 3) + 8 * (r >> 2) + 4 * hf;
    ob[(ne * 32 + m31) * AST + mi * 32 + rr] = f2bf(Cv[r] + bbv);
  }
  __syncthreads();
#pragma unroll
  for (int rep = 0; rep < 2; ++rep) {
    int idx = rep * 256 + t, row = idx >> 3, c8 = (idx & 7) * 8;  // row = e
    *(uint4*)&Vtg[obaseT + (size_t)row * MM + c8] = *(uint4*)&ob[row * AST + c8];
  }
}

// ---------------- Kernel 2: flash attention, S^T + shfl, prefetch pipeline ----------
// grid (16, H, N), 256 thr = 4 waves: wave w -> ih = w>>1 (i-tile), jh = w&1 (j-half).
__global__ __launch_bounds__(256, 4) void attn_kernel(
    const unsigned short* __restrict__ Kf, const unsigned short* __restrict__ Qf,
    const unsigned short* __restrict__ Vtg, const float* __restrict__ x,
    unsigned short* __restrict__ DX) {
  __shared__ unsigned short smem[2 * 64 * AST];  // qh | vt ; end: red float[4608]
  __shared__ float lsp[2][64];
  unsigned short* qh = smem;             // Q f16 [j_local][e]
  unsigned short* vt = smem + 64 * AST;  // V^T bf16 [e][j_local]

  const int t = threadIdx.x;
  const int w = t >> 6, lane = t & 63, m31 = lane & 31, hf = lane >> 5;
  const int ih = w >> 1, jh = w & 1;
  const int i0 = blockIdx.x * 64, h = blockIdx.y, n = blockIdx.z;
  const size_t base = (((size_t)n * HH + h) * MM) * DD;
  const size_t baseT = (((size_t)n * HH + h) * DD) * MM;
  const int irow = i0 + ih * 32 + m31;
  const int srow0 = t >> 3, srow1 = srow0 + 32, c8 = (t & 7) * 8;

  // K B-frags (f16, pre-scaled by log2e)
  f16x8 kf[4];
#pragma unroll
  for (int ks = 0; ks < 4; ++ks)
    kf[ks] = *(const f16x8*)&Kf[base + (size_t)irow * DD + ks * 16 + hf * 8];

  f32x16 agg0, agg1;
#pragma unroll
  for (int r = 0; r < 16; ++r) { agg0[r] = 0.f; agg1[r] = 0.f; }
  float lsum = 0.f;

  // prefetch tile 0
  uint4 rq0 = *(const uint4*)&Qf[base + (size_t)srow0 * DD + c8];
  uint4 rq1 = *(const uint4*)&Qf[base + (size_t)srow1 * DD + c8];
  uint4 rv0 = *(const uint4*)&Vtg[baseT + (size_t)srow0 * MM + c8];
  uint4 rv1 = *(const uint4*)&Vtg[baseT + (size_t)srow1 * MM + c8];

  for (int jt = 0; jt < 16; ++jt) {
    __syncthreads();  // prev tile's readers done
    *(uint4*)&qh[srow0 * AST + c8] = rq0;
    *(uint4*)&qh[srow1 * AST + c8] = rq1;
    *(uint4*)&vt[srow0 * AST + c8] = rv0;
    *(uint4*)&vt[srow1 * AST + c8] = rv1;
    __syncthreads();  // staging visible
    if (jt < 15) {    // prefetch next tile; VMEM overlaps compute below
      const int j1 = (jt + 1) * 64;
      rq0 = *(const uint4*)&Qf[base + (size_t)(j1 + srow0) * DD + c8];
      rq1 = *(const uint4*)&Qf[base + (size_t)(j1 + srow1) * DD + c8];
      rv0 = *(const uint4*)&Vtg[baseT + (size_t)srow0 * MM + j1 + c8];
      rv1 = *(const uint4*)&Vtg[baseT + (size_t)srow1 * MM + j1 + c8];
    }

    // S^T for this j-half: C[r] = S'[i=irow][j] with S' = log2e * S
    f32x16 C;
#pragma unroll
    for (int r = 0; r < 16; ++r) C[r] = 0.f;
#pragma unroll
    for (int ks = 0; ks < 4; ++ks) {
      f16x8 qa = *(f16x8*)&qh[(jh * 32 + m31) * AST + ks * 16 + hf * 8];
      C = __builtin_amdgcn_mfma_f32_32x32x16_f16(qa, kf[ks], C, 0, 0, 0);
    }
    unsigned int pk[8];
#pragma unroll
    for (int g = 0; g < 4; ++g) {
      float p0 = C[4 * g + 0], p1 = C[4 * g + 1], p2 = C[4 * g + 2], p3 = C[4 * g + 3];
      p0 = __builtin_amdgcn_exp2f(fmaxf(p0, NEG * p0));
      p1 = __builtin_amdgcn_exp2f(fmaxf(p1, NEG * p1));
      p2 = __builtin_amdgcn_exp2f(fmaxf(p2, NEG * p2));
      p3 = __builtin_amdgcn_exp2f(fmaxf(p3, NEG * p3));
      lsum += (p0 + p1) + (p2 + p3);
      pk[g * 2]     = pack_bf16_tr(p0, p1);
      pk[g * 2 + 1] = pack_bf16_tr(p2, p3);
    }

    // PV over this j-half: A-frags via lane^32 exchange
#pragma unroll
    for (int kk = 0; kk < 2; ++kk) {
      const int gl2 = kk * 4, gh2 = kk * 4 + 2;
      unsigned int sA = hf ? pk[gl2]     : pk[gh2];
      unsigned int sB = hf ? pk[gl2 + 1] : pk[gh2 + 1];
      unsigned int rA = (unsigned int)__shfl_xor((int)sA, 32);
      unsigned int rB = (unsigned int)__shfl_xor((int)sB, 32);
      union { unsigned int u[4]; bf16x8 v; } cv;
      cv.u[0] = hf ? rA : pk[gl2];
      cv.u[1] = hf ? rB : pk[gl2 + 1];
      cv.u[2] = hf ? pk[gh2]     : rA;
      cv.u[3] = hf ? pk[gh2 + 1] : rB;
      bf16x8 bV0 = *(bf16x8*)&vt[m31 * AST + jh * 32 + kk * 16 + hf * 8];
      bf16x8 bV1 = *(bf16x8*)&vt[(32 + m31) * AST + jh * 32 + kk * 16 + hf * 8];
      agg0 = __builtin_amdgcn_mfma_f32_32x32x16_bf16(cv.v, bV0, agg0, 0, 0, 0);
      agg1 = __builtin_amdgcn_mfma_f32_32x32x16_bf16(cv.v, bV1, agg1, 0, 0, 0);
    }
  }

  lsum += __shfl_xor(lsum, 32);
  __syncthreads();  // PV reads done; smem reusable
  if (hf == 0) lsp[jh][ih * 32 + m31] = lsum;
  float* red = (float*)smem;
  const int slot = ih * 2304 + m31 * 72 + hf * 36;
  if (jh == 1) {
#pragma unroll
    for (int c = 0; c < 4; ++c) {
      *(float4*)&red[slot + 4 * c]      = make_float4(agg0[4*c], agg0[4*c+1], agg0[4*c+2], agg0[4*c+3]);
      *(float4*)&red[slot + 16 + 4 * c] = make_float4(agg1[4*c], agg1[4*c+1], agg1[4*c+2], agg1[4*c+3]);
    }
  }
  __syncthreads();
  if (jh == 0) {
#pragma unroll
    for (int c = 0; c < 4; ++c) {
      float4 v0 = *(float4*)&red[slot + 4 * c];
      float4 v1 = *(float4*)&red[slot + 16 + 4 * c];
      agg0[4*c] += v0.x; agg0[4*c+1] += v0.y; agg0[4*c+2] += v0.z; agg0[4*c+3] += v0.w;
      agg1[4*c] += v1.x; agg1[4*c+1] += v1.y; agg1[4*c+2] += v1.z; agg1[4*c+3] += v1.w;
    }
    float invl[16];
#pragma unroll
    for (int r = 0; r < 16; ++r) {
      int rr = (r & 3) + 8 * (r >> 2) + 4 * hf;
      invl[r] = 1.0f / (lsp[0][ih * 32 + rr] + lsp[1][ih * 32 + rr]);
    }
#pragma unroll
    for (int r = 0; r < 16; ++r) {
      int rr = (r & 3) + 8 * (r >> 2) + 4 * hf;
      const size_t row = (size_t)n * MM + i0 + ih * 32 + rr;
      float v0 = agg0[r] * invl[r];
      v0 = fmaxf(v0, NEG * v0);
      v0 -= x[row * DD + m31];
      DX[row * (HH * DD) + h * DD + m31] = f2h(v0);
      float v1 = agg1[r] * invl[r];
      v1 = fmaxf(v1, NEG * v1);
      v1 -= x[row * DD + 32 + m31];
      DX[row * (HH * DD) + h * DD + 32 + m31] = f2h(v1);
    }
  }
}

// ---------------- Kernel 3: decoder, LDS-free direct-gather MFMA ----------------
// grid 512 x 128 thr (2 waves: nd = col-half). FULL K=256: 16 MFMA (the R7/R8
// bug was stopping at 8 -> K=128, dropping heads 2-3).
__global__ __launch_bounds__(128) void dec_kernel(
    const unsigned short* __restrict__ DX, const unsigned short* __restrict__ Wdf,
    const float* __restrict__ bdec, float* __restrict__ out) {
  const int t = threadIdx.x;
  const int nd = t >> 6, lane = t & 63, m31 = lane & 31, hf = lane >> 5;
  const int r0 = blockIdx.x * 32;
  f32x16 C;
#pragma unroll
  for (int r = 0; r < 16; ++r) C[r] = 0.f;
#pragma unroll
  for (int ks = 0; ks < 16; ++ks) {
    f16x8 aD = *(const f16x8*)&DX[(size_t)(r0 + m31) * 256 + ks * 16 + hf * 8];
    f16x8 bW = *(const f16x8*)&Wdf[(size_t)(nd * 32 + m31) * 256 + ks * 16 + hf * 8];
    C = __builtin_amdgcn_mfma_f32_32x32x16_f16(aD, bW, C, 0, 0, 0);
  }
  const float bb = bdec[nd * 32 + m31];
#pragma unroll
  for (int r = 0; r < 16; ++r) {
    int rr = (r & 3) + 8 * (r >> 2) + 4 * hf;
    out[(size_t)(r0 + rr) * DD + nd * 32 + m31] = C[r] + bb;
  }
}

extern "C" void kernel_launch(void* const* d_in, const int* in_sizes, int n_in,
                              void* d_out, int out_size, void* d_ws, size_t ws_size,
                              hipStream_t stream) {
  const float* x    = (const float*)d_in[0];
  const float* Wk   = (const float*)d_in[2];
  const float* bk   = (const float*)d_in[3];
  const float* Wq   = (const float*)d_in[4];
  const float* bq   = (const float*)d_in[5];
  const float* Wv   = (const float*)d_in[6];
  const float* bv   = (const float*)d_in[7];
  const float* Wdec = (const float*)d_in[8];
  const float* bdec = (const float*)d_in[9];
  float* out = (float*)d_out;

  // ws (shorts): Kf | Qf | Vt | DX (each N*H*M*D = 4,194,304) | Wdf (16384)
  const size_t seg = (size_t)NB * HH * MM * DD;
  unsigned short* Kf  = (unsigned short*)d_ws;
  unsigned short* Qf  = Kf + seg;
  unsigned short* Vt  = Qf + seg;
  unsigned short* DXp = Vt + seg;
  unsigned short* Wdf = DXp + seg;

  proj_kernel<<<dim3(256, HH), 256, 0, stream>>>(x, Wk, Wq, Wv, bk, bq, bv, Wdec,
                                                 Kf, Qf, Vt, Wdf);
  attn_kernel<<<dim3(16, HH, NB), 256, 0, stream>>>(Kf, Qf, Vt, x, DXp);
  dec_kernel<<<NB * MM / 32, 128, 0, stream>>>(DXp, Wdf, bdec, out);
}